// Round 3
// baseline (3180.666 us; speedup 1.0000x reference)
//
#include <hip/hip_runtime.h>
#include <hip/hip_cooperative_groups.h>

namespace cg = cooperative_groups;

// 2D acoustic FDTD, persistent cooperative kernel, one grid sync per step.
// State (h1, h2, c2*dt2/dx2) lives in registers; h1 is mirrored to a
// double-buffered global field so neighbor blocks can read stencil halos.
// OUTPUT LAYOUT (from reference): y = transpose(recs,(0,2,1)) with recs
// (nt,B,R)  ->  y shape (nt, R, B), flat = t*R*B + r*B + b.

constexpr int B_   = 4;
constexpr int NY   = 256;
constexpr int NX   = 256;
constexpr int NT   = 300;
constexpr int RCV  = 128;

constexpr int BPB  = 16;              // row-chunks per batch
constexpr int RPB  = NY / BPB;        // 16 rows per block
constexpr int NBLK = B_ * BPB;        // 64 blocks
constexpr int NTHR = 256;             // 16 rows x 16 col-groups of 16 cells
constexpr int FIELD = B_ * NY * NX;   // floats per time level

__global__ __launch_bounds__(NTHR, 1)
void wave_persistent(const float* __restrict__ x,      // B x NT
                     const float* __restrict__ vp,     // NY x NX
                     const int*   __restrict__ src_y,  // B
                     const int*   __restrict__ src_x,  // B
                     const int*   __restrict__ rec_y,  // R
                     const int*   __restrict__ rec_x,  // R
                     float*       __restrict__ y,      // NT x R x B  (!)
                     float*       __restrict__ buf)    // 2 * FIELD scratch
{
    cg::grid_group grid = cg::this_grid();

    const int tid   = threadIdx.x;
    const int blk   = blockIdx.x;
    const int b     = blk >> 4;            // / BPB
    const int chunk = blk & (BPB - 1);
    const int row   = chunk * RPB + (tid >> 4);
    const int col0  = (tid & 15) * 16;
    const int rowbase = row * NX + col0;

    const int sy = src_y[b], sx = src_x[b];
    const bool has_src = (row == sy) && (sx >= col0) && (sx < col0 + 16);

    // receiver indices (hoisted; blocks 0..3 gather batch==blk, lanes <128)
    int ry = 0, rx = 0;
    const bool gatherer = (blk < B_) && (tid < RCV);
    if (gatherer) { ry = rec_y[tid]; rx = rec_x[tid]; }

    // folded coefficient: vp^2 * dt^2 / dx^2
    const float scale = (0.001f * 0.001f) / (10.0f * 10.0f);
    float h1[16], h2[16], c2[16];
#pragma unroll
    for (int i = 0; i < 16; i += 4) {
        float4 v = *reinterpret_cast<const float4*>(&vp[rowbase + i]);
        c2[i + 0] = v.x * v.x * scale;
        c2[i + 1] = v.y * v.y * scale;
        c2[i + 2] = v.z * v.z * scale;
        c2[i + 3] = v.w * v.w * scale;
    }
#pragma unroll
    for (int i = 0; i < 16; ++i) { h1[i] = 0.f; h2[i] = 0.f; }

    // zero both field buffers in-kernel (d_ws arrives poisoned)
    const float4 z4 = make_float4(0.f, 0.f, 0.f, 0.f);
#pragma unroll
    for (int half = 0; half < 2; ++half) {
        float* p = buf + half * FIELD + b * NY * NX + rowbase;
#pragma unroll
        for (int i = 0; i < 16; i += 4)
            *reinterpret_cast<float4*>(&p[i]) = z4;
    }
    grid.sync();

    const float* xb = x + b * NT;

    for (int t = 0; t < NT; ++t) {
        const float* cur  = buf + (t & 1) * FIELD;         // holds h(t)
        float*       nxt  = buf + ((t + 1) & 1) * FIELD;   // receives h(t+1)
        const float* curb = cur + b * NY * NX;
        float*       nxtb = nxt + b * NY * NX;

        // --- stencil halo reads from global (zero-padded boundaries) ---
        float u[16], d[16];
        if (row > 0) {
#pragma unroll
            for (int i = 0; i < 16; i += 4)
                *reinterpret_cast<float4*>(&u[i]) =
                    *reinterpret_cast<const float4*>(&curb[rowbase - NX + i]);
        } else {
#pragma unroll
            for (int i = 0; i < 16; ++i) u[i] = 0.f;
        }
        if (row < NY - 1) {
#pragma unroll
            for (int i = 0; i < 16; i += 4)
                *reinterpret_cast<float4*>(&d[i]) =
                    *reinterpret_cast<const float4*>(&curb[rowbase + NX + i]);
        } else {
#pragma unroll
            for (int i = 0; i < 16; ++i) d[i] = 0.f;
        }
        const float lft = (col0 > 0)       ? curb[rowbase - 1]  : 0.f;
        const float rgt = (col0 + 16 < NX) ? curb[rowbase + 16] : 0.f;

        const float xt = xb[t];

        // --- leapfrog update (h1 center/left/right from registers) ---
        float hn[16];
#pragma unroll
        for (int i = 0; i < 16; ++i) {
            const float l = (i == 0)  ? lft : h1[i - 1];
            const float r = (i == 15) ? rgt : h1[i + 1];
            hn[i] = 2.f * h1[i] - h2[i] + c2[i] * (u[i] + d[i] + l + r - 4.f * h1[i]);
        }
        if (has_src) {
#pragma unroll
            for (int i = 0; i < 16; ++i)
                if (i == sx - col0) hn[i] += xt;   // compile-time reg index
        }

        // publish h(t+1) for neighbor blocks; rotate register state
#pragma unroll
        for (int i = 0; i < 16; i += 4)
            *reinterpret_cast<float4*>(&nxtb[rowbase + i]) =
                *reinterpret_cast<const float4*>(&hn[i]);
#pragma unroll
        for (int i = 0; i < 16; ++i) { h2[i] = h1[i]; h1[i] = hn[i]; }

        grid.sync();   // h(t+1) globally visible

        // --- receiver gather for step t: y[t, r, b] = t*R*B + r*B + b ---
        if (gatherer)
            y[(t * RCV + tid) * B_ + blk] = nxt[blk * NY * NX + ry * NX + rx];
    }
}

extern "C" void kernel_launch(void* const* d_in, const int* in_sizes, int n_in,
                              void* d_out, int out_size, void* d_ws, size_t ws_size,
                              hipStream_t stream) {
    const float* x     = (const float*)d_in[0];
    const float* vp    = (const float*)d_in[1];
    const int*   src_y = (const int*)d_in[2];
    const int*   src_x = (const int*)d_in[3];
    const int*   rec_y = (const int*)d_in[4];
    const int*   rec_x = (const int*)d_in[5];
    float*       y     = (float*)d_out;
    float*       buf   = (float*)d_ws;   // 2 * FIELD floats = 2 MiB

    void* args[] = {(void*)&x, (void*)&vp, (void*)&src_y, (void*)&src_x,
                    (void*)&rec_y, (void*)&rec_x, (void*)&y, (void*)&buf};
    hipLaunchCooperativeKernel((void*)wave_persistent, dim3(NBLK), dim3(NTHR),
                               args, 0, stream);
}

// Round 4
// 917.954 us; speedup vs baseline: 3.4649x; 3.4649x over previous
//
#include <hip/hip_runtime.h>

// 2D acoustic FDTD, 16 persistent blocks (4 per batch), field LDS-resident.
// Cross-block halo exchange via tiny global buffers + per-block monotonic
// flags (release/acquire, agent scope) — NO grid-wide sync, no field traffic.
// Output layout (from reference): y[t, r, b] = t*R*B + r*B + b.

constexpr int B_   = 4;
constexpr int NY   = 256;
constexpr int NX   = 256;
constexpr int NT   = 300;
constexpr int RCV  = 128;

constexpr int QB   = 4;               // blocks per batch
constexpr int RB   = NY / QB;         // 64 rows per block
constexpr int NBLK = B_ * QB;         // 16 blocks
constexpr int NTHR = 1024;            // 16 waves: wave = 4 rows x 256 cols
constexpr int SLABR = RB + 2;         // +2 halo rows

constexpr int HALO_FLOATS = B_ * QB * 2 * 2 * NX;   // [b][q][edge][slot][NX]

__global__ __launch_bounds__(NTHR, 1)
void wave16(const float* __restrict__ x,      // B x NT
            const float* __restrict__ vp,     // NY x NX
            const int*   __restrict__ src_y,  // B
            const int*   __restrict__ src_x,  // B
            const int*   __restrict__ rec_y,  // R
            const int*   __restrict__ rec_x,  // R
            float*       __restrict__ y,      // NT x R x B
            float*       __restrict__ halo,   // HALO_FLOATS (zeroed)
            int*         __restrict__ flags)  // NBLK (zeroed)
{
    __shared__ float slab[SLABR][NX];          // h(t), rows 1..64 own, 0/65 halo

    const int tid  = threadIdx.x;
    const int blk  = blockIdx.x;
    const int b    = blk >> 2, q = blk & 3;
    const int r0   = q * RB;
    const int w    = tid >> 6;                 // wave id: rows 4w..4w+3
    const int lane = tid & 63;
    const int c0   = lane * 4;                 // 4 consecutive cols per lane
    const int srow = 4 * w + 1;                // slab row of tile-row 0

    // zero slab (d_ws-independent; LDS starts undefined)
    for (int i = tid; i < SLABR * NX; i += NTHR) ((float*)slab)[i] = 0.f;

    // coefficients + state in registers
    const float scale = 1e-6f / 100.0f;        // dt^2/dx^2
    float h1[4][4], h2[4][4], c2[4][4];
#pragma unroll
    for (int i = 0; i < 4; ++i) {
        float4 v = *reinterpret_cast<const float4*>(&vp[(r0 + 4 * w + i) * NX + c0]);
        c2[i][0] = v.x * v.x * scale;
        c2[i][1] = v.y * v.y * scale;
        c2[i][2] = v.z * v.z * scale;
        c2[i][3] = v.w * v.w * scale;
#pragma unroll
        for (int j = 0; j < 4; ++j) { h1[i][j] = 0.f; h2[i][j] = 0.f; }
    }

    // source ownership (compile-time-unrolled injection below)
    const int sy = src_y[b], sx = src_x[b];
    const bool src_mine = (sy >= r0 + 4 * w) && (sy < r0 + 4 * w + 4) && ((sx >> 2) == lane);
    const int s_i = sy & 3, s_j = sx & 3;

    // receiver ownership: threads 64..191 handle receiver r = tid-64
    bool  rec_mine = false; int rec_sidx = 0; float* yp = nullptr;
    if (tid >= 64 && tid < 64 + RCV) {
        const int r  = tid - 64;
        const int ry = rec_y[r], rx = rec_x[r];
        rec_mine = (ry >= r0) && (ry < r0 + RB);
        rec_sidx = (ry - r0 + 1) * NX + rx;
        yp = y + r * B_ + b;
    }

    // halo pointers: layout offset = (((b*QB+q)*2 + edge)*2 + slot)*NX
    float*       pub_top = halo + (((b * QB + q) * 2 + 0) * 2) * NX;
    float*       pub_bot = halo + (((b * QB + q) * 2 + 1) * 2) * NX;
    const float* up_src  = (q > 0)      ? halo + (((b * QB + q - 1) * 2 + 1) * 2) * NX : nullptr;
    const float* dn_src  = (q < QB - 1) ? halo + (((b * QB + q + 1) * 2 + 0) * 2) * NX : nullptr;
    int* myflag = flags + blk;
    int* upflag = flags + blk - 1;
    int* dnflag = flags + blk + 1;

    const float* xb = x + b * NT;

    __syncthreads();   // slab zero visible

    for (int t = 0; t < NT; ++t) {
        const int  slot = (t + 1) & 1;
        const float xt  = xb[t];

        // inter-wave vertical halos of h(t) from LDS (full-wave contiguous b128)
        float4 u4 = *reinterpret_cast<const float4*>(&slab[srow - 1][c0]);
        float4 d4 = *reinterpret_cast<const float4*>(&slab[srow + 4][c0]);
        const float ua[4] = {u4.x, u4.y, u4.z, u4.w};
        const float da[4] = {d4.x, d4.y, d4.z, d4.w};

        // leapfrog update; l/r across lanes via shuffle, vertical via regs
        float hn[4][4];
#pragma unroll
        for (int i = 0; i < 4; ++i) {
            float lv = __shfl_up(h1[i][3], 1);   if (lane == 0)  lv = 0.f;
            float rv = __shfl_down(h1[i][0], 1); if (lane == 63) rv = 0.f;
#pragma unroll
            for (int j = 0; j < 4; ++j) {
                const float u = (i == 0) ? ua[j] : h1[i - 1][j];
                const float d = (i == 3) ? da[j] : h1[i + 1][j];
                const float l = (j == 0) ? lv : h1[i][j - 1];
                const float r = (j == 3) ? rv : h1[i][j + 1];
                const float lap = u + d + l + r - 4.f * h1[i][j];
                hn[i][j] = 2.f * h1[i][j] - h2[i][j] + c2[i][j] * lap;
            }
        }
        if (src_mine) {
#pragma unroll
            for (int i = 0; i < 4; ++i)
#pragma unroll
                for (int j = 0; j < 4; ++j)
                    if (i == s_i && j == s_j) hn[i][j] += xt;
        }

        // publish edge rows of h(t+1) to global halo buffer
        if (w == 0)
            *reinterpret_cast<float4*>(&pub_top[slot * NX + c0]) =
                make_float4(hn[0][0], hn[0][1], hn[0][2], hn[0][3]);
        if (w == 15)
            *reinterpret_cast<float4*>(&pub_bot[slot * NX + c0]) =
                make_float4(hn[3][0], hn[3][1], hn[3][2], hn[3][3]);

        __syncthreads();   // all h(t) slab reads done; publish stores drained

        if (tid == 0) {
            __threadfence();   // push halo stores to device coherence point
            __hip_atomic_store(myflag, t + 1, __ATOMIC_RELEASE, __HIP_MEMORY_SCOPE_AGENT);
        }

        // write h(t+1) into slab; rotate register state
#pragma unroll
        for (int i = 0; i < 4; ++i) {
            *reinterpret_cast<float4*>(&slab[srow + i][c0]) =
                make_float4(hn[i][0], hn[i][1], hn[i][2], hn[i][3]);
#pragma unroll
            for (int j = 0; j < 4; ++j) { h2[i][j] = h1[i][j]; h1[i][j] = hn[i][j]; }
        }

        __syncthreads();   // slab h(t+1) complete

        // ingest neighbor halos (spin on neighbor flag), gather receivers
        if (w == 0 && q > 0) {
            while (__hip_atomic_load(upflag, __ATOMIC_RELAXED, __HIP_MEMORY_SCOPE_AGENT) < t + 1)
                __builtin_amdgcn_s_sleep(2);
            __builtin_amdgcn_fence(__ATOMIC_ACQUIRE, "agent");
            float4 v = *reinterpret_cast<const float4*>(&up_src[slot * NX + c0]);
            *reinterpret_cast<float4*>(&slab[0][c0]) = v;
        }
        if (w == 15 && q < QB - 1) {
            while (__hip_atomic_load(dnflag, __ATOMIC_RELAXED, __HIP_MEMORY_SCOPE_AGENT) < t + 1)
                __builtin_amdgcn_s_sleep(2);
            __builtin_amdgcn_fence(__ATOMIC_ACQUIRE, "agent");
            float4 v = *reinterpret_cast<const float4*>(&dn_src[slot * NX + c0]);
            *reinterpret_cast<float4*>(&slab[SLABR - 1][c0]) = v;
        }
        if (rec_mine)
            yp[t * RCV * B_] = ((const float*)slab)[rec_sidx];

        __syncthreads();   // halo rows + gather done before next step
    }
}

extern "C" void kernel_launch(void* const* d_in, const int* in_sizes, int n_in,
                              void* d_out, int out_size, void* d_ws, size_t ws_size,
                              hipStream_t stream) {
    const float* x     = (const float*)d_in[0];
    const float* vp    = (const float*)d_in[1];
    const int*   src_y = (const int*)d_in[2];
    const int*   src_x = (const int*)d_in[3];
    const int*   rec_y = (const int*)d_in[4];
    const int*   rec_x = (const int*)d_in[5];
    float*       y     = (float*)d_out;

    float* halo  = (float*)d_ws;
    int*   flags = (int*)((char*)d_ws + (size_t)HALO_FLOATS * sizeof(float));

    // zero halo buffers + flags (deterministic per call / per graph replay)
    hipMemsetAsync(d_ws, 0, (size_t)HALO_FLOATS * sizeof(float) + NBLK * sizeof(int), stream);

    wave16<<<NBLK, NTHR, 0, stream>>>(x, vp, src_y, src_x, rec_y, rec_x,
                                      y, halo, flags);
}

// Round 5
// 598.684 us; speedup vs baseline: 5.3128x; 1.5333x over previous
//
#include <hip/hip_runtime.h>

// 2D acoustic FDTD with temporal blocking (trapezoid, W=8).
// 16 persistent blocks (4 per batch, 64 own rows + 8-row overlap each side).
// Cross-block exchange of 8-wide halos every 8 steps via global buffers +
// monotonic flags (release/acquire, agent scope). Field slab in LDS; state in
// registers (5 rows x 4 cols per thread, ping-pong arrays, in-place update).
// Output layout: y[t, r, b] = t*R*B + r*B + b.

constexpr int B_   = 4;
constexpr int NY   = 256;
constexpr int NX   = 256;
constexpr int NT   = 300;
constexpr int RCV  = 128;

constexpr int QB   = 4;                // blocks per batch
constexpr int RB   = NY / QB;          // 64 own rows
constexpr int W    = 8;                // temporal block depth / halo width
constexpr int EXT  = RB + 2 * W;       // 80 extended rows
constexpr int NBLK = B_ * QB;          // 16
constexpr int NTHR = 1024;             // 16 waves; wave w owns ext rows [5w,5w+5)
constexpr int ROWS = EXT / 16;         // 5 rows per thread
constexpr int SLABR = EXT + 2;         // 82 (+2 zero pad rows)
constexpr int PUBR = 15;               // 8 rows h(T) + 7 rows h(T-1)
constexpr int LINKS = B_ * (QB - 1);   // 12
constexpr int HALO_FLOATS = LINKS * 2 * 2 * PUBR * NX;  // link,dir,slot

__global__ __launch_bounds__(NTHR, 4)
void wave_tb(const float* __restrict__ x,      // B x NT
             const float* __restrict__ vp,     // NY x NX
             const int*   __restrict__ src_y,  // B
             const int*   __restrict__ src_x,  // B
             const int*   __restrict__ rec_y,  // R
             const int*   __restrict__ rec_x,  // R
             float*       __restrict__ y,      // NT x R x B
             float*       __restrict__ halo,   // HALO_FLOATS (zeroed)
             int*         __restrict__ flags)  // NBLK (zeroed)
{
    __shared__ float slab[SLABR][NX];   // h(t) ext rows at s=ext+1; rows 0,81 stay 0

    const int tid = threadIdx.x, blk = blockIdx.x;
    const int b = blk >> 2, q = blk & 3;
    const int r0 = q * RB;
    const int w = tid >> 6, lane = tid & 63;
    const int c0 = lane * 4;
    const int e0 = ROWS * w;            // first ext row owned by this thread

    for (int i = tid; i < SLABR * NX; i += NTHR) ((float*)slab)[i] = 0.f;

    // c2 = vp^2 * dt^2 / dx^2 ; void rows (outside domain) get c2=0 -> stay 0
    const float scale = 1e-8f;
    float hA[ROWS][4], hB[ROWS][4], c2[ROWS][4];
#pragma unroll
    for (int rr = 0; rr < ROWS; ++rr) {
        const int gr = r0 - W + e0 + rr;
        if (gr >= 0 && gr < NY) {
            float4 v = *reinterpret_cast<const float4*>(&vp[gr * NX + c0]);
            c2[rr][0] = v.x * v.x * scale; c2[rr][1] = v.y * v.y * scale;
            c2[rr][2] = v.z * v.z * scale; c2[rr][3] = v.w * v.w * scale;
        } else {
#pragma unroll
            for (int j = 0; j < 4; ++j) c2[rr][j] = 0.f;
        }
#pragma unroll
        for (int j = 0; j < 4; ++j) { hA[rr][j] = 0.f; hB[rr][j] = 0.f; }
    }

    const int sy = src_y[b], sx = src_x[b];
    const int es = sy - r0 + W;          // source ext row (may be out of range)
    const bool src_mine = (es >= e0) && (es < e0 + ROWS) && ((sx >> 2) == lane);

    bool rec_mine = false; int rec_addr = 0; float* yp = nullptr;
    if (tid < RCV) {
        const int ry = rec_y[tid], rx = rec_x[tid];
        rec_mine = (ry >= r0) && (ry < r0 + RB);
        rec_addr = (ry - r0 + W + 1) * NX + rx;
        yp = y + tid * B_ + b;
    }

    const float* xb = x + b * NT;
    int* upflag = flags + blk - 1;       // valid iff q>0
    int* dnflag = flags + blk + 1;       // valid iff q<3

    __syncthreads();
    int exch = 0;

// One leapfrog step: HO = h(t) (read), HN holds h(t-1) and is overwritten
// in place with h(t+1). All register indices are compile-time constants.
#define STEP(HO, HN, tt)                                                       \
    {                                                                          \
        const float4 u4 = *reinterpret_cast<const float4*>(&slab[e0][c0]);     \
        const float4 d4 = *reinterpret_cast<const float4*>(&slab[e0+ROWS+1][c0]);\
        const float ua[4] = {u4.x, u4.y, u4.z, u4.w};                          \
        const float da[4] = {d4.x, d4.y, d4.z, d4.w};                          \
        const float xt = xb[tt];                                               \
        _Pragma("unroll")                                                      \
        for (int rr = 0; rr < ROWS; ++rr) {                                    \
            float lv = __shfl_up(HO[rr][3], 1);   if (lane == 0)  lv = 0.f;    \
            float rv = __shfl_down(HO[rr][0], 1); if (lane == 63) rv = 0.f;    \
            _Pragma("unroll")                                                  \
            for (int j = 0; j < 4; ++j) {                                      \
                const float uu = (rr == 0)        ? ua[j] : HO[rr-1][j];       \
                const float dd = (rr == ROWS-1)   ? da[j] : HO[rr+1][j];       \
                const float ll = (j == 0) ? lv : HO[rr][j-1];                  \
                const float rv2= (j == 3) ? rv : HO[rr][j+1];                  \
                HN[rr][j] = 2.f*HO[rr][j] - HN[rr][j]                          \
                          + c2[rr][j]*(uu + dd + ll + rv2 - 4.f*HO[rr][j]);    \
            }                                                                  \
        }                                                                      \
        if (src_mine) {                                                        \
            _Pragma("unroll")                                                  \
            for (int rr = 0; rr < ROWS; ++rr) {                                \
                _Pragma("unroll")                                              \
                for (int j = 0; j < 4; ++j)                                    \
                    if (e0 + rr == es && j == (sx & 3)) HN[rr][j] += xt;       \
            }                                                                  \
        }                                                                      \
        __syncthreads();   /* all slab h(t) reads done */                      \
        _Pragma("unroll")                                                      \
        for (int rr = 0; rr < ROWS; ++rr)                                      \
            *reinterpret_cast<float4*>(&slab[e0+1+rr][c0]) =                   \
                make_float4(HN[rr][0], HN[rr][1], HN[rr][2], HN[rr][3]);       \
        __syncthreads();   /* slab = h(t+1) */                                 \
        if (rec_mine) yp[(tt) * RCV * B_] = ((const float*)slab)[rec_addr];    \
        if ((((tt) + 1) & 7) == 0) {                                           \
            ++exch;                                                            \
            const int slot = exch & 1;                                         \
            if (q < QB-1 && tid < 512) {   /* bottom pub h1: ext[64,72) */     \
                float* p = halo + ((((b*3+q)*2 + 0)*2 + slot)*PUBR)*NX;        \
                const int row = tid >> 6, cf = (tid & 63) * 4;                 \
                *reinterpret_cast<float4*>(&p[row*NX + cf]) =                  \
                    *reinterpret_cast<const float4*>(&slab[65 + row][cf]);     \
            }                                                                  \
            if (q > 0 && tid >= 512) {     /* top pub h1: ext[8,16) */         \
                float* p = halo + ((((b*3+q-1)*2 + 1)*2 + slot)*PUBR)*NX;      \
                const int i2 = tid - 512;                                      \
                const int row = i2 >> 6, cf = (i2 & 63) * 4;                   \
                *reinterpret_cast<float4*>(&p[row*NX + cf]) =                  \
                    *reinterpret_cast<const float4*>(&slab[9 + row][cf]);      \
            }                                                                  \
            if (q < QB-1) {                /* bottom pub h(T-1): ext[65,72) */ \
                float* p = halo + ((((b*3+q)*2 + 0)*2 + slot)*PUBR)*NX;        \
                _Pragma("unroll")                                              \
                for (int rr = 0; rr < ROWS; ++rr) {                            \
                    const int ext = e0 + rr;                                   \
                    if (ext >= 65 && ext < 72)                                 \
                        *reinterpret_cast<float4*>(&p[(8+ext-65)*NX + c0]) =   \
                            make_float4(HO[rr][0],HO[rr][1],HO[rr][2],HO[rr][3]);\
                }                                                              \
            }                                                                  \
            if (q > 0) {                   /* top pub h(T-1): ext[8,15) */     \
                float* p = halo + ((((b*3+q-1)*2 + 1)*2 + slot)*PUBR)*NX;      \
                _Pragma("unroll")                                              \
                for (int rr = 0; rr < ROWS; ++rr) {                            \
                    const int ext = e0 + rr;                                   \
                    if (ext >= 8 && ext < 15)                                  \
                        *reinterpret_cast<float4*>(&p[(8+ext-8)*NX + c0]) =    \
                            make_float4(HO[rr][0],HO[rr][1],HO[rr][2],HO[rr][3]);\
                }                                                              \
            }                                                                  \
            __syncthreads();               /* pub stores drained (vmcnt) */    \
            if (tid == 0) {                                                    \
                __threadfence();           /* L2 writeback, agent scope */     \
                __hip_atomic_store(&flags[blk], exch, __ATOMIC_RELEASE,        \
                                   __HIP_MEMORY_SCOPE_AGENT);                  \
            }                                                                  \
            if (q > 0 && w <= 1) {         /* top ingest: ext[0,8) */          \
                while (__hip_atomic_load(upflag, __ATOMIC_RELAXED,             \
                        __HIP_MEMORY_SCOPE_AGENT) < exch)                      \
                    __builtin_amdgcn_s_sleep(1);                               \
                __builtin_amdgcn_fence(__ATOMIC_ACQUIRE, "agent");             \
                const float* p = halo + ((((b*3+q-1)*2 + 0)*2 + slot)*PUBR)*NX;\
                _Pragma("unroll")                                              \
                for (int rr = 0; rr < ROWS; ++rr) {                            \
                    const int ext = e0 + rr;                                   \
                    if (ext < 8) {                                             \
                        float4 v = *reinterpret_cast<const float4*>(           \
                            &p[ext*NX + c0]);                                  \
                        HN[rr][0]=v.x; HN[rr][1]=v.y; HN[rr][2]=v.z; HN[rr][3]=v.w;\
                        *reinterpret_cast<float4*>(&slab[ext+1][c0]) = v;      \
                        if (ext >= 1) {                                        \
                            float4 v2 = *reinterpret_cast<const float4*>(      \
                                &p[(7+ext)*NX + c0]);                          \
                            HO[rr][0]=v2.x; HO[rr][1]=v2.y;                    \
                            HO[rr][2]=v2.z; HO[rr][3]=v2.w;                    \
                        }                                                      \
                    }                                                          \
                }                                                              \
            }                                                                  \
            if (q < QB-1 && w >= 14) {     /* bottom ingest: ext[72,80) */     \
                while (__hip_atomic_load(dnflag, __ATOMIC_RELAXED,             \
                        __HIP_MEMORY_SCOPE_AGENT) < exch)                      \
                    __builtin_amdgcn_s_sleep(1);                               \
                __builtin_amdgcn_fence(__ATOMIC_ACQUIRE, "agent");             \
                const float* p = halo + ((((b*3+q)*2 + 1)*2 + slot)*PUBR)*NX;  \
                _Pragma("unroll")                                              \
                for (int rr = 0; rr < ROWS; ++rr) {                            \
                    const int ext = e0 + rr;                                   \
                    if (ext >= 72) {                                           \
                        float4 v = *reinterpret_cast<const float4*>(           \
                            &p[(ext-72)*NX + c0]);                             \
                        HN[rr][0]=v.x; HN[rr][1]=v.y; HN[rr][2]=v.z; HN[rr][3]=v.w;\
                        *reinterpret_cast<float4*>(&slab[ext+1][c0]) = v;      \
                        if (ext < 79) {                                        \
                            float4 v2 = *reinterpret_cast<const float4*>(      \
                                &p[(8+ext-72)*NX + c0]);                       \
                            HO[rr][0]=v2.x; HO[rr][1]=v2.y;                    \
                            HO[rr][2]=v2.z; HO[rr][3]=v2.w;                    \
                        }                                                      \
                    }                                                          \
                }                                                              \
            }                                                                  \
            __syncthreads();               /* ingested slab rows visible */    \
        }                                                                      \
    }

    for (int t = 0; t < NT; t += 2) {
        STEP(hA, hB, t)        // hB: h(t-1) -> h(t+1)
        STEP(hB, hA, t + 1)    // hA: h(t)   -> h(t+2)
    }
#undef STEP
}

extern "C" void kernel_launch(void* const* d_in, const int* in_sizes, int n_in,
                              void* d_out, int out_size, void* d_ws, size_t ws_size,
                              hipStream_t stream) {
    const float* x     = (const float*)d_in[0];
    const float* vp    = (const float*)d_in[1];
    const int*   src_y = (const int*)d_in[2];
    const int*   src_x = (const int*)d_in[3];
    const int*   rec_y = (const int*)d_in[4];
    const int*   rec_x = (const int*)d_in[5];
    float*       y     = (float*)d_out;

    float* halo  = (float*)d_ws;
    int*   flags = (int*)((char*)d_ws + (size_t)HALO_FLOATS * sizeof(float));

    // zero halo + flags (deterministic per call / per graph replay)
    hipMemsetAsync(d_ws, 0,
                   (size_t)HALO_FLOATS * sizeof(float) + NBLK * sizeof(int),
                   stream);

    wave_tb<<<NBLK, NTHR, 0, stream>>>(x, vp, src_y, src_x, rec_y, rec_x,
                                       y, halo, flags);
}

// Round 6
// 365.787 us; speedup vs baseline: 8.6954x; 1.6367x over previous
//
#include <hip/hip_runtime.h>

// 2D acoustic FDTD, temporal blocking (trapezoid W=8), 64 persistent blocks
// (16 per batch, 16 own rows + 8 halo rows each side = 32 ext rows).
// Double-buffered LDS slab -> ONE __syncthreads per step.
// Cross-block exchange every 8 steps: agent-scope relaxed atomics (8B),
// cache-bypassing, no threadfence (no L1/L2 wipe). Monotonic flags.
// State in registers: 4 rows x 4 cols per thread (ping-pong in-place).
// Output layout: y[t, r, b] = t*R*B + r*B + b.

constexpr int B_   = 4;
constexpr int NY   = 256;
constexpr int NX   = 256;
constexpr int NT   = 300;
constexpr int RCV  = 128;

constexpr int QB   = 16;               // blocks per batch
constexpr int RB   = NY / QB;          // 16 own rows
constexpr int W    = 8;                // temporal depth / halo width
constexpr int EXT  = RB + 2 * W;       // 32 ext rows
constexpr int NBLK = B_ * QB;          // 64 blocks
constexpr int NTHR = 512;              // 8 waves x (4 rows x 256 cols)
constexpr int ROWS = 4;                // ext rows per thread
constexpr int NW   = EXT / ROWS;       // 8 waves
constexpr int SLABR = EXT + 2;         // 34 (+2 zero pads)
constexpr int PUBR = 2 * W - 1;        // 15: rows 0..7 h(T), 8..14 h(T-1)
constexpr int LINKS = B_ * (QB - 1);   // 60
constexpr size_t HALO_FLOATS = (size_t)LINKS * 2 * 2 * PUBR * NX;

__device__ __forceinline__ void at_store2(float* p, float a, float b) {
    float2 v = make_float2(a, b);
    unsigned long long u;
    __builtin_memcpy(&u, &v, 8);
    __hip_atomic_store((unsigned long long*)p, u, __ATOMIC_RELAXED,
                       __HIP_MEMORY_SCOPE_AGENT);
}
__device__ __forceinline__ float2 at_load2(const float* p) {
    unsigned long long u = __hip_atomic_load((const unsigned long long*)p,
                                             __ATOMIC_RELAXED,
                                             __HIP_MEMORY_SCOPE_AGENT);
    float2 v;
    __builtin_memcpy(&v, &u, 8);
    return v;
}

__global__ __launch_bounds__(NTHR, 1)
void wave_tb2(const float* __restrict__ x,      // B x NT
              const float* __restrict__ vp,     // NY x NX
              const int*   __restrict__ src_y,  // B
              const int*   __restrict__ src_x,  // B
              const int*   __restrict__ rec_y,  // R
              const int*   __restrict__ rec_x,  // R
              float*       __restrict__ y,      // NT x R x B
              float*       __restrict__ halo,   // HALO_FLOATS
              int*         __restrict__ flags)  // NBLK (zeroed)
{
    __shared__ float slabs[2][SLABR][NX];   // slot = t&1 holds h(t); rows 0,33 = 0

    const int tid = threadIdx.x, blk = blockIdx.x;
    const int b = blk >> 4, q = blk & 15;
    const int r0 = q * RB;
    const int w = tid >> 6, lane = tid & 63;
    const int c0 = lane * 4;
    const int e0 = ROWS * w;                 // first ext row of this thread/wave

    for (int i = tid; i < 2 * SLABR * NX; i += NTHR) ((float*)slabs)[i] = 0.f;

    // c2 = vp^2 * dt^2 / dx^2; rows outside domain get c2=0 (cells stay 0)
    const float scale = 1e-8f;
    float hA[ROWS][4], hB[ROWS][4], c2[ROWS][4];
#pragma unroll
    for (int rr = 0; rr < ROWS; ++rr) {
        const int gr = r0 - W + e0 + rr;
        if (gr >= 0 && gr < NY) {
            float4 v = *reinterpret_cast<const float4*>(&vp[gr * NX + c0]);
            c2[rr][0] = v.x * v.x * scale; c2[rr][1] = v.y * v.y * scale;
            c2[rr][2] = v.z * v.z * scale; c2[rr][3] = v.w * v.w * scale;
        } else {
#pragma unroll
            for (int j = 0; j < 4; ++j) c2[rr][j] = 0.f;
        }
#pragma unroll
        for (int j = 0; j < 4; ++j) { hA[rr][j] = 0.f; hB[rr][j] = 0.f; }
    }

    // source: inject at ANY ext cell matching global (sy,sx) (halo replicas too)
    const int sy = src_y[b], sx = src_x[b];
    const int es = sy - r0 + W;
    const bool src_mine = (es >= e0) && (es < e0 + ROWS) && ((sx >> 2) == lane);
    const int s_j = sx & 3;

    bool rec_mine = false; int rec_addr = 0; float* yp = nullptr;
    if (tid < RCV) {
        const int ry = rec_y[tid], rx = rec_x[tid];
        rec_mine = (ry >= r0) && (ry < r0 + RB);
        rec_addr = (ry - r0 + W + 1) * NX + rx;     // slab rows [9,25)
        yp = y + tid * B_ + b;
    }

    const float* xb = x + b * NT;
    int* upflag = flags + blk - 1;   // valid iff q>0
    int* dnflag = flags + blk + 1;   // valid iff q<QB-1

    __syncthreads();
    int exch = 0;

#define STEP(HO, HN, tt)                                                       \
    {                                                                          \
        const int cur = (tt) & 1, nxt = ((tt) + 1) & 1;                        \
        if ((tt) > 0 && rec_mine)      /* gather h(tt) = output index tt-1 */  \
            yp[(size_t)((tt) - 1) * RCV * B_] =                                \
                ((const float*)slabs[cur])[rec_addr];                          \
        const float4 u4 = *reinterpret_cast<const float4*>(&slabs[cur][e0][c0]);\
        const float4 d4 = *reinterpret_cast<const float4*>(&slabs[cur][e0+ROWS+1][c0]);\
        const float ua[4] = {u4.x, u4.y, u4.z, u4.w};                          \
        const float da[4] = {d4.x, d4.y, d4.z, d4.w};                          \
        const float xt = xb[tt];                                               \
        _Pragma("unroll")                                                      \
        for (int rr = 0; rr < ROWS; ++rr) {                                    \
            float lv = __shfl_up(HO[rr][3], 1);   if (lane == 0)  lv = 0.f;    \
            float rv = __shfl_down(HO[rr][0], 1); if (lane == 63) rv = 0.f;    \
            _Pragma("unroll")                                                  \
            for (int j = 0; j < 4; ++j) {                                      \
                const float uu = (rr == 0)      ? ua[j] : HO[rr-1][j];         \
                const float dd = (rr == ROWS-1) ? da[j] : HO[rr+1][j];         \
                const float ll = (j == 0) ? lv : HO[rr][j-1];                  \
                const float rr2= (j == 3) ? rv : HO[rr][j+1];                  \
                HN[rr][j] = 2.f*HO[rr][j] - HN[rr][j]                          \
                          + c2[rr][j]*(uu + dd + ll + rr2 - 4.f*HO[rr][j]);    \
            }                                                                  \
        }                                                                      \
        if (src_mine) {                                                        \
            _Pragma("unroll")                                                  \
            for (int rr = 0; rr < ROWS; ++rr)                                  \
                _Pragma("unroll")                                              \
                for (int j = 0; j < 4; ++j)                                    \
                    if (e0 + rr == es && j == s_j) HN[rr][j] += xt;            \
        }                                                                      \
        _Pragma("unroll")                                                      \
        for (int rr = 0; rr < ROWS; ++rr)                                      \
            *reinterpret_cast<float4*>(&slabs[nxt][e0+1+rr][c0]) =             \
                make_float4(HN[rr][0], HN[rr][1], HN[rr][2], HN[rr][3]);       \
        if ((((tt) + 1) & 7) == 0) {                                           \
            ++exch;                                                            \
            const int slot = exch & 1;                                         \
            if (q < QB-1 && w >= 4 && w <= 5) {      /* bottom pub: ext[16,24) */\
                float* p = halo + (((size_t)(b*(QB-1)+q)*2 + 0)*2 + slot)*PUBR*NX;\
                _Pragma("unroll")                                              \
                for (int rr = 0; rr < ROWS; ++rr) {                            \
                    const int ext = e0 + rr;                                   \
                    at_store2(&p[(ext-16)*NX + c0],     HN[rr][0], HN[rr][1]); \
                    at_store2(&p[(ext-16)*NX + c0 + 2], HN[rr][2], HN[rr][3]); \
                    if (ext >= 17) {                                           \
                        at_store2(&p[(8+ext-17)*NX + c0],     HO[rr][0], HO[rr][1]);\
                        at_store2(&p[(8+ext-17)*NX + c0 + 2], HO[rr][2], HO[rr][3]);\
                    }                                                          \
                }                                                              \
            }                                                                  \
            if (q > 0 && w >= 2 && w <= 3) {         /* top pub: ext[8,16) */  \
                float* p = halo + (((size_t)(b*(QB-1)+q-1)*2 + 1)*2 + slot)*PUBR*NX;\
                _Pragma("unroll")                                              \
                for (int rr = 0; rr < ROWS; ++rr) {                            \
                    const int ext = e0 + rr;                                   \
                    at_store2(&p[(ext-8)*NX + c0],     HN[rr][0], HN[rr][1]);  \
                    at_store2(&p[(ext-8)*NX + c0 + 2], HN[rr][2], HN[rr][3]);  \
                    if (ext < 15) {                                            \
                        at_store2(&p[(8+ext-8)*NX + c0],     HO[rr][0], HO[rr][1]);\
                        at_store2(&p[(8+ext-8)*NX + c0 + 2], HO[rr][2], HO[rr][3]);\
                    }                                                          \
                }                                                              \
            }                                                                  \
            __syncthreads();   /* drains vmcnt (atomic stores) + LDS writes */ \
            if (tid == 0)                                                      \
                __hip_atomic_store(&flags[blk], exch, __ATOMIC_RELAXED,        \
                                   __HIP_MEMORY_SCOPE_AGENT);                  \
            if (q > 0 && w <= 1) {                   /* top ingest: ext[0,8) */\
                while (__hip_atomic_load(upflag, __ATOMIC_RELAXED,             \
                        __HIP_MEMORY_SCOPE_AGENT) < exch)                      \
                    __builtin_amdgcn_s_sleep(1);                               \
                const float* p = halo + (((size_t)(b*(QB-1)+q-1)*2 + 0)*2 + slot)*PUBR*NX;\
                _Pragma("unroll")                                              \
                for (int rr = 0; rr < ROWS; ++rr) {                            \
                    const int ext = e0 + rr;                                   \
                    float2 a0 = at_load2(&p[ext*NX + c0]);                     \
                    float2 a1 = at_load2(&p[ext*NX + c0 + 2]);                 \
                    HN[rr][0]=a0.x; HN[rr][1]=a0.y; HN[rr][2]=a1.x; HN[rr][3]=a1.y;\
                    *reinterpret_cast<float4*>(&slabs[nxt][ext+1][c0]) =       \
                        make_float4(a0.x, a0.y, a1.x, a1.y);                   \
                    if (ext >= 1) {                                            \
                        float2 b0 = at_load2(&p[(8+ext-1)*NX + c0]);           \
                        float2 b1 = at_load2(&p[(8+ext-1)*NX + c0 + 2]);       \
                        HO[rr][0]=b0.x; HO[rr][1]=b0.y; HO[rr][2]=b1.x; HO[rr][3]=b1.y;\
                    }                                                          \
                }                                                              \
            }                                                                  \
            if (q < QB-1 && w >= NW-2) {             /* bottom ingest: ext[24,32) */\
                while (__hip_atomic_load(dnflag, __ATOMIC_RELAXED,             \
                        __HIP_MEMORY_SCOPE_AGENT) < exch)                      \
                    __builtin_amdgcn_s_sleep(1);                               \
                const float* p = halo + (((size_t)(b*(QB-1)+q)*2 + 1)*2 + slot)*PUBR*NX;\
                _Pragma("unroll")                                              \
                for (int rr = 0; rr < ROWS; ++rr) {                            \
                    const int ext = e0 + rr;                                   \
                    float2 a0 = at_load2(&p[(ext-24)*NX + c0]);                \
                    float2 a1 = at_load2(&p[(ext-24)*NX + c0 + 2]);            \
                    HN[rr][0]=a0.x; HN[rr][1]=a0.y; HN[rr][2]=a1.x; HN[rr][3]=a1.y;\
                    *reinterpret_cast<float4*>(&slabs[nxt][ext+1][c0]) =       \
                        make_float4(a0.x, a0.y, a1.x, a1.y);                   \
                    if (ext < 31) {                                            \
                        float2 b0 = at_load2(&p[(8+ext-24)*NX + c0]);          \
                        float2 b1 = at_load2(&p[(8+ext-24)*NX + c0 + 2]);      \
                        HO[rr][0]=b0.x; HO[rr][1]=b0.y; HO[rr][2]=b1.x; HO[rr][3]=b1.y;\
                    }                                                          \
                }                                                              \
            }                                                                  \
            __syncthreads();   /* ingested slab rows + regs ready */           \
        } else {                                                               \
            __syncthreads();   /* h(tt+1) slab complete */                     \
        }                                                                      \
    }

    for (int t = 0; t < NT; t += 2) {
        STEP(hA, hB, t)        // hB: h(t-1) -> h(t+1)
        STEP(hB, hA, t + 1)    // hA: h(t)   -> h(t+2)
    }
#undef STEP

    // final gather: h(NT) lives in slot NT&1 = 0; output index NT-1
    if (rec_mine)
        yp[(size_t)(NT - 1) * RCV * B_] = ((const float*)slabs[0])[rec_addr];
}

extern "C" void kernel_launch(void* const* d_in, const int* in_sizes, int n_in,
                              void* d_out, int out_size, void* d_ws, size_t ws_size,
                              hipStream_t stream) {
    const float* x     = (const float*)d_in[0];
    const float* vp    = (const float*)d_in[1];
    const int*   src_y = (const int*)d_in[2];
    const int*   src_x = (const int*)d_in[3];
    const int*   rec_y = (const int*)d_in[4];
    const int*   rec_x = (const int*)d_in[5];
    float*       y     = (float*)d_out;

    float* halo  = (float*)d_ws;
    int*   flags = (int*)((char*)d_ws + HALO_FLOATS * sizeof(float));

    hipMemsetAsync(d_ws, 0, HALO_FLOATS * sizeof(float) + NBLK * sizeof(int),
                   stream);

    wave_tb2<<<NBLK, NTHR, 0, stream>>>(x, vp, src_y, src_x, rec_y, rec_x,
                                        y, halo, flags);
}